// Round 1
// 463.903 us; speedup vs baseline: 1.1913x; 1.1913x over previous
//
#include <hip/hip_runtime.h>

typedef unsigned short u16;
typedef unsigned int   u32;
typedef __attribute__((ext_vector_type(8))) short short8;
typedef __attribute__((ext_vector_type(4))) float f32x4;
typedef __attribute__((ext_vector_type(4))) u16  u16x4;

#define DI __device__ __forceinline__

DI float b2f(u16 v){ return __builtin_bit_cast(float, (u32)v << 16); }
DI u16 f2b(float f){ u32 u = __builtin_bit_cast(u32, f); return (u16)((u + 0x7fffu + ((u >> 16) & 1u)) >> 16); }
DI float lrelu(float v){ return v > 0.f ? v : 0.01f * v; }

// ---------------- f32 -> bf16 conversion (inputs are float32 — proven R3) --
__global__ __launch_bounds__(256)
void cvt_bf16(const float* __restrict__ in, u16* __restrict__ out, int n4)
{
  int i = blockIdx.x*256 + threadIdx.x;
  if (i >= n4) return;
  float4 v = ((const float4*)in)[i];
  u16x4 o; o[0]=f2b(v.x); o[1]=f2b(v.y); o[2]=f2b(v.z); o[3]=f2b(v.w);
  *(u16x4*)(out + (size_t)i*4) = o;
}

// ---------------- GEMM (NT): Y[M,N] = A[M,K] * W[N,K]^T, f32 out -----------
template<int BM, int BN, int WROWS, int WCOLS, int RT, int CT>
__global__ __launch_bounds__(WROWS*WCOLS*64)
void gemm_nt(const u16* __restrict__ A, const u16* __restrict__ W,
             float* __restrict__ Y, int M, int N, int K)
{
  constexpr int NT  = WROWS*WCOLS*64;
  constexpr int ALD = (BM*4)/NT;
  constexpr int BLD = (BN*4)/NT;
  __shared__ __align__(16) u16 As[BM*32];
  __shared__ __align__(16) u16 Bs[BN*32];
  const int tid  = threadIdx.x;
  const int wave = tid >> 6, lane = tid & 63;
  const int wr = wave / WCOLS, wc = wave % WCOLS;
  const int lrow = lane & 15, kg = lane >> 4;
  const int m0 = blockIdx.x * BM, n0 = blockIdx.y * BN;
  f32x4 acc[RT][CT] = {};
  for (int k0 = 0; k0 < K; k0 += 32) {
    uint4 av[ALD], bv[BLD];
#pragma unroll
    for (int i = 0; i < ALD; i++){ int x = tid + i*NT; av[i] = *(const uint4*)(A + (size_t)(m0 + (x>>2))*K + k0 + (x&3)*8); }
#pragma unroll
    for (int i = 0; i < BLD; i++){ int x = tid + i*NT; bv[i] = *(const uint4*)(W + (size_t)(n0 + (x>>2))*K + k0 + (x&3)*8); }
    __syncthreads();
#pragma unroll
    for (int i = 0; i < ALD; i++){ *(uint4*)(As + (tid + i*NT)*8) = av[i]; }
#pragma unroll
    for (int i = 0; i < BLD; i++){ *(uint4*)(Bs + (tid + i*NT)*8) = bv[i]; }
    __syncthreads();
    short8 af[RT], bfr[CT];
#pragma unroll
    for (int r = 0; r < RT; r++) af[r]  = *(const short8*)(As + ((wr*RT + r)*16 + lrow)*32 + kg*8);
#pragma unroll
    for (int c = 0; c < CT; c++) bfr[c] = *(const short8*)(Bs + ((wc*CT + c)*16 + lrow)*32 + kg*8);
#pragma unroll
    for (int r = 0; r < RT; r++)
#pragma unroll
      for (int c = 0; c < CT; c++)
        acc[r][c] = __builtin_amdgcn_mfma_f32_16x16x32_bf16(af[r], bfr[c], acc[r][c], 0, 0, 0);
  }
  // C/D: col=lane&15, row=(lane>>4)*4+i  [m89/m91]
#pragma unroll
  for (int r = 0; r < RT; r++)
#pragma unroll
    for (int c = 0; c < CT; c++)
#pragma unroll
      for (int i = 0; i < 4; i++){
        int m = m0 + (wr*RT + r)*16 + kg*4 + i;
        int n = n0 + (wc*CT + c)*16 + lrow;
        Y[(size_t)m*N + n] = acc[r][c][i];
      }
}

// ---------------- BatchNorm (training-mode, batch stats), Y f32 ------------
__global__ __launch_bounds__(256)
void bn_partial(const float* __restrict__ Y, float* __restrict__ part, int N, int rowsPer)
{
  const int tx = threadIdx.x & 63, ty = threadIdx.x >> 6;
  const int n  = blockIdx.x*64 + tx;
  const int m0 = blockIdx.y * rowsPer;
  float s = 0.f, s2 = 0.f;
  for (int m = m0 + ty; m < m0 + rowsPer; m += 4){ float v = Y[(size_t)m*N + n]; s += v; s2 += v*v; }
  __shared__ float ls[4][64], ls2[4][64];
  ls[ty][tx] = s; ls2[ty][tx] = s2;
  __syncthreads();
  if (ty == 0){
    s  = ls[0][tx]+ls[1][tx]+ls[2][tx]+ls[3][tx];
    s2 = ls2[0][tx]+ls2[1][tx]+ls2[2][tx]+ls2[3][tx];
    part[(size_t)(blockIdx.y*2+0)*N + n] = s;
    part[(size_t)(blockIdx.y*2+1)*N + n] = s2;
  }
}

__global__ __launch_bounds__(256)
void bn_finalize(const float* __restrict__ part, const float* __restrict__ g,
                 const float* __restrict__ be, float* __restrict__ ss, int N, int M, int split)
{
  int n = blockIdx.x*256 + threadIdx.x;
  if (n >= N) return;
  float s = 0.f, s2 = 0.f;
  for (int i = 0; i < split; i++){ s += part[(size_t)(i*2+0)*N + n]; s2 += part[(size_t)(i*2+1)*N + n]; }
  float inv  = 1.f / (float)M;
  float mean = s * inv;
  float var  = fmaxf(s2*inv - mean*mean, 0.f);
  float sc   = g[n] * rsqrtf(var + 1e-5f);
  ss[n]     = sc;
  ss[N + n] = be[n] - mean*sc;
}

__global__ __launch_bounds__(256)
void bn_apply(const float* __restrict__ Y, const float* __restrict__ ss,
              u16* __restrict__ H, int total4, int N)
{
  int i = blockIdx.x*256 + threadIdx.x;
  if (i >= total4) return;
  float4 v = ((const float4*)Y)[i];
  int nb = (i*4) & (N-1);
  u16x4 o;
  o[0] = f2b(lrelu(v.x*ss[nb+0] + ss[N+nb+0]));
  o[1] = f2b(lrelu(v.y*ss[nb+1] + ss[N+nb+1]));
  o[2] = f2b(lrelu(v.z*ss[nb+2] + ss[N+nb+2]));
  o[3] = f2b(lrelu(v.w*ss[nb+3] + ss[N+nb+3]));
  *(u16x4*)(H + (size_t)i*4) = o;
}

// BN apply layer-4 + per-sample transpose: Xt[b][n][c] = lrelu(bn(h4))[b][c*64+n]
__global__ __launch_bounds__(256)
void bn_apply4_t(const float* __restrict__ Y, const float* __restrict__ ss, u16* __restrict__ Xt)
{
  const int b = blockIdx.x, tid = threadIdx.x;
  __shared__ u16 t[64*65];
  for (int j = tid; j < 4096; j += 256){
    float v = Y[(size_t)b*4096 + j];
    v = lrelu(v*ss[j] + ss[4096 + j]);
    int c = j >> 6, n = j & 63;
    t[c*65 + n] = f2b(v);
  }
  __syncthreads();
  for (int e = tid; e < 4096; e += 256){
    int n = e >> 6, c = e & 63;
    Xt[(size_t)b*4096 + n*64 + c] = t[c*65 + n];
  }
}

// ---------------- conv weight repack: MFMA-fragment order ------------------
// Output layout: chunk (tr, kb) of 512 u16 = 64 lanes x 8 elems, contiguous.
//   wr[ ((tr*NK + kb)*64 + lane)*8 + j ] = w[row][c*3 + k]
//   row = tr*16 + (lane&15); kcol = kb*32 + (lane>>4)*8 + j; k = kcol>>lgC; c = kcol&(C-1)
// so the in-kernel A-fragment load is one fully coalesced 1024B wave read.
__global__ __launch_bounds__(256)
void repack_w_frag(const float* __restrict__ w, u16* __restrict__ wr, int O, int C, int lgC)
{
  int e = blockIdx.x*256 + threadIdx.x;
  int R = 3*C;
  if (e >= O*R) return;
  int NK   = R >> 5;
  int j    = e & 7;
  int lane = (e >> 3) & 63;
  int blk  = e >> 9;               // tr*NK + kb
  int tr   = blk / NK, kb = blk - tr*NK;
  int row  = tr*16 + (lane & 15);
  int kcol = kb*32 + (lane >> 4)*8 + j;
  int k = kcol >> lgC; int c = kcol & (C-1);
  wr[e] = f2b(w[(size_t)row*R + c*3 + k]);
}

// ---------------- tree-conv + TreeLayerNorm + LeakyReLU --------------------
// Xin: (B, 64, C) bf16 node-major. non-LAST out: (B, 64, O) bf16. LAST: (B,O,64) f32.
// v2: fragment-ordered coalesced weight loads + 2-stage register pipeline + setprio.
template<int C, int O, bool LAST>
__global__ __launch_bounds__(512)
void conv_norm(const u16* __restrict__ Xin, const u16* __restrict__ Wr,
               const float* __restrict__ cb, const int* __restrict__ gidx,
               u16* __restrict__ Xout, float* __restrict__ Outf)
{
  constexpr int R    = 3*C;
  constexpr int NK   = R/32;               // 32-wide K blocks (6 / 12 / 24)
  constexpr int CSI  = C + 8;
  constexpr int RT   = O/128;
  constexpr int LGC  = (C==64)?6:((C==128)?7:8);
  constexpr int LG32 = LGC - 5;            // kb32 -> tap index shift
  __shared__ __align__(16) u16 xs[65*CSI];
  __shared__ int idxs[192];
  __shared__ float red[16];
  const int b = blockIdx.x, tid = threadIdx.x;
  const int wave = tid >> 6, lane = tid & 63;
  const int lrow = lane & 15, kg = lane >> 4;

  const u16* xg = Xin + (size_t)b*64*C;
  for (int e = tid; e < 64*(C/8); e += 512){
    int row = e/(C/8), t = e%(C/8);
    *(uint4*)(xs + row*CSI + t*8) = *(const uint4*)(xg + row*C + t*8);
  }
  for (int e = tid; e < C/8; e += 512){ uint4 z = {0,0,0,0}; *(uint4*)(xs + 64*CSI + e*8) = z; }
  if (tid < 189){ int v = gidx[b*189 + tid]; idxs[tid] = v & 63; }
  __syncthreads();

  // gathered node row per (output-node ct, tap k), kept in separate register
  // arrays so tap selection is two cndmasks — no scratch (rule #20).
  int jr0[4], jr1[4], jr2[4];
#pragma unroll
  for (int ct = 0; ct < 4; ct++){
    int n = ct*16 + lrow;
    jr0[ct] = (n == 0) ? 64 : idxs[3*(n-1) + 0];
    jr1[ct] = (n == 0) ? 64 : idxs[3*(n-1) + 1];
    jr2[ct] = (n == 0) ? 64 : idxs[3*(n-1) + 2];
  }

  const u16* wbase = Wr + ((size_t)wave*NK << 9) + lane*8;  // coalesced frag base (r=0)

  short8 afA[RT], bfA[4], afB[RT], bfB[4];

  auto loadA = [&](short8* af, int kb32){
#pragma unroll
    for (int r = 0; r < RT; r++)
      af[r] = *(const short8*)(wbase + (((size_t)(8*r)*NK + kb32) << 9));
  };
  auto loadB = [&](short8* bfr, int kb32){
    const int k  = kb32 >> LG32;
    const int c0 = ((kb32*32) & (C-1)) + kg*8;
#pragma unroll
    for (int ct = 0; ct < 4; ct++){
      int row = (k == 0) ? jr0[ct] : ((k == 1) ? jr1[ct] : jr2[ct]);
      bfr[ct] = *(const short8*)(xs + row*CSI + c0);
    }
  };

  f32x4 acc[RT][4] = {};
  auto domfma = [&](short8* af, short8* bfr){
    __builtin_amdgcn_s_setprio(1);
#pragma unroll
    for (int r = 0; r < RT; r++)
#pragma unroll
      for (int ct = 0; ct < 4; ct++)
        acc[r][ct] = __builtin_amdgcn_mfma_f32_16x16x32_bf16(af[r], bfr[ct], acc[r][ct], 0, 0, 0);
    __builtin_amdgcn_s_setprio(0);
  };

  loadA(afA, 0); loadB(bfA, 0);
  for (int kb32 = 0; kb32 < NK; kb32 += 2){      // NK always even (6/12/24)
    loadA(afB, kb32+1); loadB(bfB, kb32+1);      // prefetch odd stage
    domfma(afA, bfA);
    if (kb32 + 2 < NK){ loadA(afA, kb32+2); loadB(bfA, kb32+2); }  // prefetch next even
    domfma(afB, bfB);
  }

  // bias (skip null column 0) + per-sample stats over (O x 64)
  float s = 0.f, s2 = 0.f;
#pragma unroll
  for (int r = 0; r < RT; r++)
#pragma unroll
    for (int i = 0; i < 4; i++){
      int o = (wave + 8*r)*16 + kg*4 + i;
      float bias = cb[o];
#pragma unroll
      for (int ct = 0; ct < 4; ct++){
        int n = ct*16 + lrow;
        float v = acc[r][ct][i];
        if (n != 0) v += bias;
        acc[r][ct][i] = v;
        s += v; s2 += v*v;
      }
    }
#pragma unroll
  for (int off = 32; off > 0; off >>= 1){ s += __shfl_down(s, off); s2 += __shfl_down(s2, off); }
  if (lane == 0){ red[wave] = s; red[8 + wave] = s2; }
  __syncthreads();
  if (tid == 0){
    float S = 0.f, S2 = 0.f;
    for (int w = 0; w < 8; w++){ S += red[w]; S2 += red[8 + w]; }
    const float NV = (float)(O*64);
    float mean = S / NV;
    float var  = fmaxf(S2/NV - mean*mean, 0.f) * (NV/(NV-1.f));  // torch.std ddof=1
    float sc   = 1.f / (sqrtf(var) + 1e-5f);
    red[0] = mean; red[1] = sc;
  }
  __syncthreads();
  const float mean = red[0], sc = red[1];

  if constexpr (LAST) {
#pragma unroll
    for (int r = 0; r < RT; r++)
#pragma unroll
      for (int ct = 0; ct < 4; ct++)
#pragma unroll
        for (int i = 0; i < 4; i++){
          int o = (wave + 8*r)*16 + kg*4 + i;
          int n = ct*16 + lrow;
          Outf[(size_t)b*(O*64) + o*64 + n] = lrelu((acc[r][ct][i] - mean)*sc);  // f32 output
        }
  } else {
#pragma unroll
    for (int r = 0; r < RT; r++)
#pragma unroll
      for (int ct = 0; ct < 4; ct++){
        int o0 = (wave + 8*r)*16 + kg*4;
        int n  = ct*16 + lrow;
        u16x4 pk;
#pragma unroll
        for (int i = 0; i < 4; i++) pk[i] = f2b(lrelu((acc[r][ct][i] - mean)*sc));
        *(u16x4*)(Xout + (size_t)b*64*O + (size_t)n*O + o0) = pk;  // (B,64,O) node-major
      }
  }
}

// ---------------------------------------------------------------------------
extern "C" void kernel_launch(void* const* d_in, const int* in_sizes, int n_in,
                              void* d_out, int out_size, void* d_ws, size_t ws_size,
                              hipStream_t stream)
{
  // ALL float inputs are float32 (proven by R3's dtype-flag experiment).
  const float* trees = (const float*)d_in[0];
  const int*   gidx  = (const int*)d_in[1];
  const float* w1 = (const float*)d_in[2];
  const float* g1 = (const float*)d_in[4];  const float* be1 = (const float*)d_in[5];
  const float* w2 = (const float*)d_in[6];
  const float* g2 = (const float*)d_in[8];  const float* be2 = (const float*)d_in[9];
  const float* w3 = (const float*)d_in[10];
  const float* g3 = (const float*)d_in[12]; const float* be3 = (const float*)d_in[13];
  const float* w4 = (const float*)d_in[14];
  const float* g4 = (const float*)d_in[16]; const float* be4 = (const float*)d_in[17];
  const float* cw1 = (const float*)d_in[18]; const float* cb1 = (const float*)d_in[19];
  const float* cw2 = (const float*)d_in[20]; const float* cb2 = (const float*)d_in[21];
  const float* cw3 = (const float*)d_in[22]; const float* cb3 = (const float*)d_in[23];
  // linear biases b1..b4 cancel under training-mode BN — unused.

  // ws (~65.6 MB): repacked conv weights + BN scratch + Xc3 (read while d_out
  // is being overwritten by the final conv — must NOT alias d_out).
  char* ws = (char*)d_ws;
  size_t off = 0;
  auto alloc = [&](size_t bytes)->char*{ char* p = ws + off; off += (bytes + 255) & ~(size_t)255; return p; };
  u16*   Wr1  = (u16*)  alloc(128*192*2);
  u16*   Wr2  = (u16*)  alloc(256*384*2);
  u16*   Wr3  = (u16*)  alloc(512*768*2);
  float* part = (float*)alloc(16*4096*4);
  float* ss1  = (float*)alloc(2*64*4);
  float* ss2  = (float*)alloc(2*256*4);
  float* ss3  = (float*)alloc(2*1024*4);
  float* ss4  = (float*)alloc(2*4096*4);
  u16*   Xc3  = (u16*)  alloc((size_t)2048*64*256*2);   // 64 MB

  // d_out is (2048,512,64) FLOAT32 = 268 MB. Host MLP-phase scratch inside it;
  // everything here is dead before the final conv overwrites all of d_out.
  float* outF = (float*)d_out;
  u16*   ob   = (u16*)d_out;                 // u16-unit view for offsets
  float* Y    = (float*)ob;                  // u16 [0, 16,777,216)  : f32 pre-BN (2048x4096)
  u16*   H1   = ob + 16777216;               // [16,777,216, 16,908,288)
  u16*   H2   = ob + 16908288;               // [.., 17,432,576)
  u16*   H3   = ob + 17432576;               // [.., 19,529,728)
  u16*   Tb   = ob + 19529728;               // [.., 19,660,800)
  u16*   Wb1  = ob + 19660800;               // [.., 19,664,896)
  u16*   Wb2  = ob + 19664896;               // [.., 19,681,280)
  u16*   Wb3  = ob + 19681280;               // [.., 19,943,424)
  u16*   Wb4  = ob + 19943424;               // [.., 24,137,728)
  u16*   Xt1  = ob + 25165824;               // [.., 33,554,432)
  u16*   Xc2  = ob + 33554432;               // [.., 50,331,648)  < 134,217,728 ✓

  // convert f32 inputs -> bf16 for MFMA
  cvt_bf16<<<(131072/4+255)/256, 256, 0, stream>>>(trees, Tb, 131072/4);
  cvt_bf16<<<(4096/4+255)/256,   256, 0, stream>>>(w1, Wb1, 4096/4);
  cvt_bf16<<<(16384/4+255)/256,  256, 0, stream>>>(w2, Wb2, 16384/4);
  cvt_bf16<<<(262144/4+255)/256, 256, 0, stream>>>(w3, Wb3, 262144/4);
  cvt_bf16<<<(4194304/4+255)/256,256, 0, stream>>>(w4, Wb4, 4194304/4);

  repack_w_frag<<<(128*192+255)/256, 256, 0, stream>>>(cw1, Wr1, 128, 64, 6);
  repack_w_frag<<<(256*384+255)/256, 256, 0, stream>>>(cw2, Wr2, 256, 128, 7);
  repack_w_frag<<<(512*768+255)/256, 256, 0, stream>>>(cw3, Wr3, 512, 256, 8);

  // MLP layer 1: (2048,64)x(64,64)^T
  gemm_nt<64,64,4,1,1,4><<<dim3(32,1), 256, 0, stream>>>(Tb, Wb1, Y, 2048, 64, 64);
  bn_partial<<<dim3(1,8), 256, 0, stream>>>(Y, part, 64, 256);
  bn_finalize<<<1, 256, 0, stream>>>(part, g1, be1, ss1, 64, 2048, 8);
  bn_apply<<<(2048*64/4+255)/256, 256, 0, stream>>>(Y, ss1, H1, 2048*64/4, 64);
  // layer 2
  gemm_nt<64,64,4,1,1,4><<<dim3(32,4), 256, 0, stream>>>(H1, Wb2, Y, 2048, 256, 64);
  bn_partial<<<dim3(4,8), 256, 0, stream>>>(Y, part, 256, 256);
  bn_finalize<<<1, 256, 0, stream>>>(part, g2, be2, ss2, 256, 2048, 8);
  bn_apply<<<(2048*256/4+255)/256, 256, 0, stream>>>(Y, ss2, H2, 2048*256/4, 256);
  // layer 3
  gemm_nt<64,64,4,1,1,4><<<dim3(32,16), 256, 0, stream>>>(H2, Wb3, Y, 2048, 1024, 256);
  bn_partial<<<dim3(16,8), 256, 0, stream>>>(Y, part, 1024, 256);
  bn_finalize<<<4, 256, 0, stream>>>(part, g3, be3, ss3, 1024, 2048, 8);
  bn_apply<<<(2048*1024/4+255)/256, 256, 0, stream>>>(Y, ss3, H3, 2048*1024/4, 1024);
  // layer 4 (128x128 tiles)
  gemm_nt<128,128,2,2,4,4><<<dim3(16,32), 256, 0, stream>>>(H3, Wb4, Y, 2048, 4096, 1024);
  bn_partial<<<dim3(64,8), 256, 0, stream>>>(Y, part, 4096, 256);
  bn_finalize<<<16, 256, 0, stream>>>(part, g4, be4, ss4, 4096, 2048, 8);
  bn_apply4_t<<<2048, 256, 0, stream>>>(Y, ss4, Xt1);

  // tree-conv stack
  conv_norm< 64,128,false><<<2048, 512, 0, stream>>>(Xt1, Wr1, cb1, gidx, Xc2, nullptr);
  conv_norm<128,256,false><<<2048, 512, 0, stream>>>(Xc2, Wr2, cb2, gidx, Xc3, nullptr);
  conv_norm<256,512,true ><<<2048, 512, 0, stream>>>(Xc3, Wr3, cb3, gidx, nullptr, outF);
}